// Round 6
// baseline (29.766 us; speedup 1.0000x reference)
//
#include <hip/hip_runtime.h>

#define N_ROWS 16384
#define NBLK 256           // 256 blocks x 4 waves = 1024 waves x 16 rows = 16384 rows
#define FLAG_K 0x9E3779B9u // arrival token; never 0x00000000 / 0xAAAAAAAA

__global__ __launch_bounds__(256) void kl_onepass(
        const float* __restrict__ loc_g,
        const float* __restrict__ loc_u,
        const float* __restrict__ scl_g,
        const float* __restrict__ scl_u,
        float* __restrict__ partials,
        unsigned* __restrict__ flags,
        float* __restrict__ out) {
    const int tid = threadIdx.x;
    const int lane = tid & 63;
    const int wave_in_blk = tid >> 6;                     // 0..3
    const int bid = blockIdx.x;
    const int wave_id = (bid << 2) | wave_in_blk;         // 0..1023
    const int group = lane >> 2;                          // row within wave's 16-row chunk
    const int sub = lane & 3;                             // float4-quad within row

    const int row = (wave_id << 4) + group;
    const int b4 = row * 16 + sub;                        // float4 index into [N,64]

    const float4* gP  = reinterpret_cast<const float4*>(loc_g);
    const float4* uP  = reinterpret_cast<const float4*>(loc_u);
    const float4* sgP = reinterpret_cast<const float4*>(scl_g);
    const float4* suP = reinterpret_cast<const float4*>(scl_u);

    // Batch-issue all 16 independent 16B loads; latency paid once.
    float4 G[4], U[4], SG[4], SU[4];
    #pragma unroll
    for (int e = 0; e < 4; ++e) {
        G[e]  = gP [b4 + 4 * e];
        SG[e] = sgP[b4 + 4 * e];
        U[e]  = uP [b4 + 4 * e];
        SU[e] = suP[b4 + 4 * e];
    }

    float A = 0.f, Gg = 0.f, G1 = 0.f, P = 0.f, R = 0.f;
    float B = 0.f, Ug = 0.f, U1 = 0.f, Q = 0.f;
    #pragma unroll
    for (int e = 0; e < 4; ++e) {
        const float* gp  = reinterpret_cast<const float*>(&G[e]);
        const float* sgp = reinterpret_cast<const float*>(&SG[e]);
        const float* up  = reinterpret_cast<const float*>(&U[e]);
        const float* sup = reinterpret_cast<const float*>(&SU[e]);
        #pragma unroll
        for (int k = 0; k < 4; ++k) {
            float g = gp[k], sg = sgp[k], u = up[k], su = sup[k];
            float sg2 = sg * sg, su2 = su * su;
            float g2 = g * g, u2 = u * u;
            float a = 0.5f / sg2;
            float b = 0.5f / su2;
            A  += a;         Gg += g * a;   G1 += g;
            P  += sg2 + g2;  R  += g2 * a + u2 * b;
            B  += b;         Ug += u * b;   U1 += u;
            Q  += su2 + u2;
        }
    }

    // Reduce 9 sums across each 4-lane group: 2 butterfly steps.
    #pragma unroll
    for (int off = 1; off < 4; off <<= 1) {
        A  += __shfl_xor(A,  off);
        Gg += __shfl_xor(Gg, off);
        G1 += __shfl_xor(G1, off);
        P  += __shfl_xor(P,  off);
        R  += __shfl_xor(R,  off);
        B  += __shfl_xor(B,  off);
        Ug += __shfl_xor(Ug, off);
        U1 += __shfl_xor(U1, off);
        Q  += __shfl_xor(Q,  off);
    }

    // Per-row pairwise total (replicated across the 4 lanes of each group).
    float S = A * Q + B * P + 64.0f * R - 2.0f * (Gg * U1 + G1 * Ug);

    // Butterfly off=4..32 sums the 16 DISTINCT groups exactly once.
    #pragma unroll
    for (int off = 4; off < 64; off <<= 1) S += __shfl_xor(S, off);

    __shared__ float lds[4];
    if (lane == 0) lds[wave_in_blk] = S;
    __syncthreads();
    if (tid == 0) {
        partials[bid] = lds[0] + lds[1] + lds[2] + lds[3];
        __threadfence();                                   // partial visible before flag
        __hip_atomic_store(&flags[bid], FLAG_K, __ATOMIC_RELEASE,
                           __HIP_MEMORY_SCOPE_AGENT);
    }
    __syncthreads();                                       // own flag stored before scan

    // Every block's wave 0 does ONE non-blocking scan of all flags. A block
    // that sees all 256 set (guaranteed true for the temporally-last writer)
    // performs the final reduce. Multiple qualifying blocks write identical
    // bytes (fixed-order double reduction) -> benign duplicate store.
    if (tid < 64) {
        unsigned f0 = __hip_atomic_load(&flags[tid],       __ATOMIC_ACQUIRE, __HIP_MEMORY_SCOPE_AGENT);
        unsigned f1 = __hip_atomic_load(&flags[tid + 64],  __ATOMIC_ACQUIRE, __HIP_MEMORY_SCOPE_AGENT);
        unsigned f2 = __hip_atomic_load(&flags[tid + 128], __ATOMIC_ACQUIRE, __HIP_MEMORY_SCOPE_AGENT);
        unsigned f3 = __hip_atomic_load(&flags[tid + 192], __ATOMIC_ACQUIRE, __HIP_MEMORY_SCOPE_AGENT);
        const bool mine = (f0 == FLAG_K) & (f1 == FLAG_K) &
                          (f2 == FLAG_K) & (f3 == FLAG_K);
        if (__all(mine)) {
            double s = 0.0;
            #pragma unroll
            for (int i = 0; i < NBLK / 64; ++i)
                s += (double)partials[tid + 64 * i];       // ordered after acquires
            #pragma unroll
            for (int off = 1; off < 64; off <<= 1) s += __shfl_xor(s, off);
            if (tid == 0)
                out[0] = (float)(0.5 * (s / ((double)N_ROWS * 4096.0)) - 0.5);
            __threadfence();                               // reads done before reset
            #pragma unroll
            for (int i = 0; i < NBLK / 64; ++i)            // self-clean for next replay
                __hip_atomic_store(&flags[tid + 64 * i], 0u, __ATOMIC_RELAXED,
                                   __HIP_MEMORY_SCOPE_AGENT);
        }
    }
}

extern "C" void kernel_launch(void* const* d_in, const int* in_sizes, int n_in,
                              void* d_out, int out_size, void* d_ws, size_t ws_size,
                              hipStream_t stream) {
    const float* loc_g = (const float*)d_in[0];   // z_loc_gs   [N,64]
    const float* loc_u = (const float*)d_in[1];   // z_loc_uns  [N,64]
    const float* scl_g = (const float*)d_in[2];   // z_scale_gs [N,64]
    const float* scl_u = (const float*)d_in[3];   // z_scale_uns[N,64]
    float* out = (float*)d_out;
    float* partials = (float*)d_ws;                           // 256 floats
    unsigned* flags = (unsigned*)((char*)d_ws + 1024);        // 256 uints

    kl_onepass<<<NBLK, 256, 0, stream>>>(loc_g, loc_u, scl_g, scl_u,
                                         partials, flags, out);
}

// Round 7
// 11.095 us; speedup vs baseline: 2.6829x; 2.6829x over previous
//
#include <hip/hip_runtime.h>

#define N_ROWS 16384
#define NBLK 128   // 128 blocks x 4 waves = 512 waves x 32 rows = 16384 rows

__global__ __launch_bounds__(256) void kl_stage1(
        const float* __restrict__ loc_g,
        const float* __restrict__ loc_u,
        const float* __restrict__ scl_g,
        const float* __restrict__ scl_u,
        float* __restrict__ partials) {
    const int tid = threadIdx.x;
    const int lane = tid & 63;
    const int wave_in_blk = tid >> 6;                     // 0..3
    const int wave_id = (blockIdx.x << 2) | wave_in_blk;  // 0..511
    const int group = lane >> 2;                          // row within 16-row pass
    const int sub = lane & 3;                             // float4-quad within row

    const float4* gP  = reinterpret_cast<const float4*>(loc_g);
    const float4* uP  = reinterpret_cast<const float4*>(loc_u);
    const float4* sgP = reinterpret_cast<const float4*>(scl_g);
    const float4* suP = reinterpret_cast<const float4*>(scl_u);

    float accS = 0.0f;   // per-lane-group: sum of per-row S over both passes

    #pragma unroll
    for (int p = 0; p < 2; ++p) {
        const int row = (wave_id << 5) + (p << 4) + group;
        const int b4 = row * 16 + sub;

        float4 G[4], U[4], SG[4], SU[4];
        #pragma unroll
        for (int e = 0; e < 4; ++e) {
            G[e]  = gP [b4 + 4 * e];
            SG[e] = sgP[b4 + 4 * e];
            U[e]  = uP [b4 + 4 * e];
            SU[e] = suP[b4 + 4 * e];
        }

        float A = 0.f, Gg = 0.f, G1 = 0.f, P = 0.f, R = 0.f;
        float B = 0.f, Ug = 0.f, U1 = 0.f, Q = 0.f;
        #pragma unroll
        for (int e = 0; e < 4; ++e) {
            const float* gp  = reinterpret_cast<const float*>(&G[e]);
            const float* sgp = reinterpret_cast<const float*>(&SG[e]);
            const float* up  = reinterpret_cast<const float*>(&U[e]);
            const float* sup = reinterpret_cast<const float*>(&SU[e]);
            #pragma unroll
            for (int k = 0; k < 4; ++k) {
                float g = gp[k], sg = sgp[k], u = up[k], su = sup[k];
                float sg2 = sg * sg, su2 = su * su;
                float g2 = g * g, u2 = u * u;
                float a = 0.5f / sg2;
                float b = 0.5f / su2;
                A  += a;         Gg += g * a;   G1 += g;
                P  += sg2 + g2;  R  += g2 * a + u2 * b;
                B  += b;         Ug += u * b;   U1 += u;
                Q  += su2 + u2;
            }
        }

        // Reduce 9 sums across each 4-lane group: 2 butterfly steps.
        #pragma unroll
        for (int off = 1; off < 4; off <<= 1) {
            A  += __shfl_xor(A,  off);
            Gg += __shfl_xor(Gg, off);
            G1 += __shfl_xor(G1, off);
            P  += __shfl_xor(P,  off);
            R  += __shfl_xor(R,  off);
            B  += __shfl_xor(B,  off);
            Ug += __shfl_xor(Ug, off);
            U1 += __shfl_xor(U1, off);
            Q  += __shfl_xor(Q,  off);
        }

        // Per-row pairwise total (replicated across the 4 lanes of the group).
        accS += A * Q + B * P + 64.0f * R - 2.0f * (Gg * U1 + G1 * Ug);
    }

    // Butterfly off=4..32 sums the 16 DISTINCT groups exactly once.
    #pragma unroll
    for (int off = 4; off < 64; off <<= 1) accS += __shfl_xor(accS, off);

    __shared__ float lds[4];
    if (lane == 0) lds[wave_in_blk] = accS;
    __syncthreads();
    if (tid == 0)
        partials[blockIdx.x] = lds[0] + lds[1] + lds[2] + lds[3];
}

__global__ void kl_stage2(const float* __restrict__ partials,
                          float* __restrict__ out) {
    double s = (double)partials[threadIdx.x] + (double)partials[threadIdx.x + 64];
    #pragma unroll
    for (int off = 1; off < 64; off <<= 1) s += __shfl_xor(s, off);
    if (threadIdx.x == 0)
        out[0] = (float)(0.5 * (s / ((double)N_ROWS * 4096.0)) - 0.5);
}

extern "C" void kernel_launch(void* const* d_in, const int* in_sizes, int n_in,
                              void* d_out, int out_size, void* d_ws, size_t ws_size,
                              hipStream_t stream) {
    const float* loc_g = (const float*)d_in[0];   // z_loc_gs   [N,64]
    const float* loc_u = (const float*)d_in[1];   // z_loc_uns  [N,64]
    const float* scl_g = (const float*)d_in[2];   // z_scale_gs [N,64]
    const float* scl_u = (const float*)d_in[3];   // z_scale_uns[N,64]
    float* out = (float*)d_out;
    float* partials = (float*)d_ws;               // 128 floats

    kl_stage1<<<NBLK, 256, 0, stream>>>(loc_g, loc_u, scl_g, scl_u, partials);
    kl_stage2<<<1, 64, 0, stream>>>(partials, out);
}